// Round 1
// baseline (814.164 us; speedup 1.0000x reference)
//
#include <hip/hip_runtime.h>

#define Fdim 128
#define Bsz  8192
#define Pn   6
#define EPSI 1e-5f
#define X2P 136       // x2 tile pitch (halves): 272 B rows, 2-way bank max (free)
#define X1P 72        // x1 half-tile pitch: 144 B rows -> 2-way max on ds_read_b128

typedef _Float16 half8  __attribute__((ext_vector_type(8)));
typedef _Float16 half4t __attribute__((ext_vector_type(4)));
typedef float    float4t __attribute__((ext_vector_type(4)));

__constant__ int PAIR_A[6] = {0,0,0,1,1,2};
__constant__ int PAIR_B[6] = {1,2,3,2,3,3};

// ---------------------------------------------------------------------------
// Kernel 1: W [128 x 16384] fp32 -> f16 MFMA B-fragments. (unchanged)
// lane = q*16+ol holds B[k=c*32+q*8+jj][n=nt*16+ol]; Wws half8 idx = c*512+nt*64+lane.
// ---------------------------------------------------------------------------
__global__ __launch_bounds__(256) void wprep(const float* __restrict__ W,
                                             _Float16* __restrict__ Wws) {
    int t    = blockIdx.x * 256 + threadIdx.x;  // 0..262143 = 512 c * 8 nt * 64 lane
    int c    = t >> 9;
    int r    = t & 511;
    int nt   = r >> 6;
    int lane = r & 63;
    int q    = lane >> 4;
    int ol   = lane & 15;
    int o    = nt * 16 + ol;
    const float4t* src = (const float4t*)(W + (size_t)o * 16384 + c * 32 + q * 8);
    float4t a0 = src[0];
    float4t a1 = src[1];
    half8 h;
    h[0] = (_Float16)a0[0]; h[1] = (_Float16)a0[1];
    h[2] = (_Float16)a0[2]; h[3] = (_Float16)a0[3];
    h[4] = (_Float16)a1[0]; h[5] = (_Float16)a1[1];
    h[6] = (_Float16)a1[2]; h[7] = (_Float16)a1[3];
    *(half8*)(Wws + (size_t)t * 8) = h;
}

// ---------------------------------------------------------------------------
// Kernel 2: per (pair, 128-row m-block, 64-col n-half). Wave grid 2x2 is now
// (wrow = m-half) x (kw = split-K j-pair): each wave computes 64 rows x 64
// cols over half of K (jc in {kw*2, kw*2+1}, all i). nt=4 -> one pk_mul per
// MFMA (was 2); W bytes/wave unchanged (1 MB). Partial accs combined via LDS
// (x2t region, dead post-loop); kw=0 waves run the epilogue.
// ---------------------------------------------------------------------------
__global__ __launch_bounds__(256, 3) void gemm(const float* __restrict__ x,
                                               const _Float16* __restrict__ Wws,
                                               _Float16* __restrict__ yws,
                                               float* __restrict__ ssum,
                                               float* __restrict__ ssq) {
    __shared__ __align__(16) _Float16 x2t[128 * X2P];    // 34816 B: 128 rows x 128 j
    __shared__ __align__(16) _Float16 x1th[128 * X1P];   // 18432 B: 128 rows x 64 i

    int bid  = blockIdx.x;
    int p    = bid >> 7;
    int rem  = bid & 127;
    int mblk = rem >> 1;          // 64 m-blocks of 128 rows
    int nh   = rem & 1;
    int m0   = mblk * 128;
    int v1   = PAIR_A[p];
    int v2   = PAIR_B[p];
    int tid  = threadIdx.x;

    // ---- stage x2 tile (full 128x128, fp32 -> f16) ------------------------
    {
        const float4t* s2p = (const float4t*)(x + ((size_t)v2 * Bsz + m0) * Fdim);
        for (int it = 0; it < 16; ++it) {
            int idx = it * 256 + tid;
            int row = idx >> 5;
            int col = (idx & 31) * 4;
            float4t b = s2p[idx];
            half4t h2; h2[0]=(_Float16)b[0]; h2[1]=(_Float16)b[1];
                       h2[2]=(_Float16)b[2]; h2[3]=(_Float16)b[3];
            *(half4t*)&x2t[row * X2P + col] = h2;
        }
    }

    int lane  = tid & 63;
    int w     = tid >> 6;
    int wrow  = w >> 1;           // m-half: rows wrow*64 + mt*16 + ...
    int kw    = w & 1;            // split-K half: jc in {kw*2, kw*2+1}
    int ol    = lane & 15;
    int q     = lane >> 4;
    int rbase = wrow * 64;

    float4t acc[4][4];
#pragma unroll
    for (int mt = 0; mt < 4; ++mt)
#pragma unroll
        for (int nt = 0; nt < 4; ++nt)
            acc[mt][nt] = (float4t){0.f, 0.f, 0.f, 0.f};

    const half8* wb = (const half8*)Wws;
    const size_t wlane = (size_t)nh * 256 + lane;   // n-half base + lane, half8 units
    const float* x1src = x + ((size_t)v1 * Bsz + m0) * Fdim;

    for (int kh = 0; kh < 2; ++kh) {
        if (kh) __syncthreads();      // all reads of previous x1 half done
        // ---- stage x1 half-tile: 128 rows x 64 i-cols ---------------------
        for (int it = 0; it < 8; ++it) {
            int idx = it * 256 + tid;
            int row = idx >> 4;
            int c4  = (idx & 15) * 4;
            float4t a = *(const float4t*)(x1src + (size_t)row * Fdim + kh * 64 + c4);
            half4t h1; h1[0]=(_Float16)a[0]; h1[1]=(_Float16)a[1];
                       h1[2]=(_Float16)a[2]; h1[3]=(_Float16)a[3];
            *(half4t*)&x1th[row * X1P + c4] = h1;
        }
        __syncthreads();

        for (int jcl = 0; jcl < 2; ++jcl) {
            int jc = kw * 2 + jcl;    // this wave's j-chunk (k-dim of MFMA)
            // x2 fragments: constant across the whole 64-i sweep of this jc
            half8 x2f[4];
#pragma unroll
            for (int mt = 0; mt < 4; ++mt)
                x2f[mt] = *(const half8*)&x2t[(rbase + mt * 16 + ol) * X2P + jc * 32 + q * 8];

            // W stream: chunk c = (kh*64+il)*4 + jc; half8 idx = c*512 + wlane + nt*64
            // -> base advances 2048 half8 per il; nt offsets (0..3072 B) fold to imm.
            size_t wbase = (size_t)(kh * 256 + jc) * 512 + wlane;
            half8 bfa[4], bfb[4];
#pragma unroll
            for (int nt = 0; nt < 4; ++nt) bfa[nt] = wb[wbase + nt * 64];
#pragma unroll
            for (int nt = 0; nt < 4; ++nt) bfb[nt] = wb[wbase + 2048 + nt * 64];

            for (int il8 = 0; il8 < 8; ++il8) {
                half8 x1f[4];
#pragma unroll
                for (int mt = 0; mt < 4; ++mt)
                    x1f[mt] = *(const half8*)&x1th[(rbase + mt * 16 + ol) * X1P + il8 * 8];
#pragma unroll
                for (int ii = 0; ii < 8; ++ii) {
                    int il  = il8 * 8 + ii;
                    int ipl = (il < 62) ? (il + 2) : 63;   // prefetch distance 2
                    half8 bn[4];
#pragma unroll
                    for (int nt = 0; nt < 4; ++nt)
                        bn[nt] = wb[wbase + (size_t)ipl * 2048 + nt * 64];
#pragma unroll
                    for (int mt = 0; mt < 4; ++mt) {
                        _Float16 sc = x1f[mt][ii];
                        half8 a = x2f[mt] * sc;    // 4 pk_mul shared by 4 MFMAs
#pragma unroll
                        for (int nt = 0; nt < 4; ++nt)
                            acc[mt][nt] = __builtin_amdgcn_mfma_f32_16x16x32_f16(a, bfa[nt], acc[mt][nt], 0, 0, 0);
                    }
#pragma unroll
                    for (int nt = 0; nt < 4; ++nt) { bfa[nt] = bfb[nt]; bfb[nt] = bn[nt]; }
                }
            }
        }
    }

    // ---- split-K combine (via x2t region, dead now) -----------------------
    __syncthreads();                  // everyone done reading x2t / x1th
    float4t* xch = (float4t*)x2t;     // 2 waves x 16 KB = 32 KB <= 34816 B
    if (kw == 1) {
#pragma unroll
        for (int mt = 0; mt < 4; ++mt)
#pragma unroll
            for (int nt = 0; nt < 4; ++nt)
                xch[wrow * 1024 + (mt * 4 + nt) * 64 + lane] = acc[mt][nt];
    }
    __syncthreads();
    if (kw == 0) {
#pragma unroll
        for (int mt = 0; mt < 4; ++mt)
#pragma unroll
            for (int nt = 0; nt < 4; ++nt)
                acc[mt][nt] += xch[wrow * 1024 + (mt * 4 + nt) * 64 + lane];

        // ---- epilogue: store y (f16) + per-o stats ------------------------
        float sum[4] = {0.f, 0.f, 0.f, 0.f};
        float sq[4]  = {0.f, 0.f, 0.f, 0.f};
#pragma unroll
        for (int mt = 0; mt < 4; ++mt) {
#pragma unroll
            for (int r = 0; r < 4; ++r) {
                size_t row = (size_t)p * Bsz + m0 + rbase + mt * 16 + q * 4 + r;
#pragma unroll
                for (int nt = 0; nt < 4; ++nt) {
                    float v = acc[mt][nt][r];
                    sum[nt] += v; sq[nt] += v * v;
                    yws[row * Fdim + nh * 64 + nt * 16 + ol] = (_Float16)v;
                }
            }
        }
#pragma unroll
        for (int nt = 0; nt < 4; ++nt) {
            sum[nt] += __shfl_xor(sum[nt], 16, 64);  sum[nt] += __shfl_xor(sum[nt], 32, 64);
            sq[nt]  += __shfl_xor(sq[nt], 16, 64);   sq[nt]  += __shfl_xor(sq[nt], 32, 64);
        }
        if (q == 0) {
#pragma unroll
            for (int nt = 0; nt < 4; ++nt) {
                atomicAdd(&ssum[p * Fdim + nh * 64 + nt * 16 + ol], sum[nt]);
                atomicAdd(&ssq [p * Fdim + nh * 64 + nt * 16 + ol], sq[nt]);
            }
        }
    }
}

// ---------------------------------------------------------------------------
// Kernel 3: BN (train-mode batch stats, biased var) + ReLU, f16 y -> fp32 out.
// ---------------------------------------------------------------------------
__global__ __launch_bounds__(256) void bnrelu(const _Float16* __restrict__ yws,
                                              const float* __restrict__ ssum,
                                              const float* __restrict__ ssq,
                                              const float* __restrict__ gamma,
                                              const float* __restrict__ beta,
                                              float* __restrict__ out) {
    __shared__ float gs[128], sh[128];
    size_t ebase = (size_t)blockIdx.x * 1024;
    int p = (int)(ebase >> 20);            // B*F = 2^20
    int t = threadIdx.x;
    if (t < 128) {
        float mean = ssum[p * Fdim + t] * (1.0f / 8192.0f);
        float var  = ssq [p * Fdim + t] * (1.0f / 8192.0f) - mean * mean;
        float g    = gamma[t] * rsqrtf(var + EPSI);
        gs[t] = g;
        sh[t] = beta[t] - g * mean;
    }
    __syncthreads();
    size_t e0 = ebase + (size_t)t * 4;
    int o0 = (int)(e0 & 127);
    half4t y = *(const half4t*)(yws + e0);
    float4t r;
#pragma unroll
    for (int l = 0; l < 4; ++l) {
        float v = fmaf(gs[o0 + l], (float)y[l], sh[o0 + l]);
        r[l] = v > 0.f ? v : 0.f;
    }
    *(float4t*)(out + e0) = r;
}

// ---------------------------------------------------------------------------
extern "C" void kernel_launch(void* const* d_in, const int* in_sizes, int n_in,
                              void* d_out, int out_size, void* d_ws, size_t ws_size,
                              hipStream_t stream) {
    const float* x     = (const float*)d_in[0];
    const float* W     = (const float*)d_in[1];
    // d_in[2] = linear bias b: mathematically cancelled by train-mode BN.
    const float* gamma = (const float*)d_in[3];
    const float* beta  = (const float*)d_in[4];
    float* out = (float*)d_out;

    char* ws = (char*)d_ws;
    _Float16* yws = (_Float16*)ws;                       // 6*8192*128*2 = 12,582,912 B
    _Float16* Wws = (_Float16*)(ws + 12582912);          // 128*16384*2  =  4,194,304 B
    float*    ssum = (float*)(ws + 16777216);            // 768 floats
    float*    ssq  = ssum + Pn * Fdim;                   // 768 floats

    (void)hipMemsetAsync(ssum, 0, 2 * Pn * Fdim * sizeof(float), stream);
    wprep<<<1024, 256, 0, stream>>>(W, Wws);
    gemm<<<768, 256, 0, stream>>>(x, Wws, yws, ssum, ssq);
    bnrelu<<<6144, 256, 0, stream>>>(yws, ssum, ssq, gamma, beta, out);
}

// Round 2
// 485.393 us; speedup vs baseline: 1.6773x; 1.6773x over previous
//
#include <hip/hip_runtime.h>

#define Fdim 128
#define Bsz  8192
#define Pn   6
#define EPSI 1e-5f
#define X2P 136       // x2 tile pitch (halves): 272 B rows, 2-way bank max (free)
#define X1P 72        // x1 half-tile pitch: 144 B rows -> 2-way max on ds_read_b128

typedef _Float16 half8  __attribute__((ext_vector_type(8)));
typedef _Float16 half4t __attribute__((ext_vector_type(4)));
typedef float    float4t __attribute__((ext_vector_type(4)));

__constant__ int PAIR_A[6] = {0,0,0,1,1,2};
__constant__ int PAIR_B[6] = {1,2,3,2,3,3};

// ---------------------------------------------------------------------------
// Kernel 1: W [128 x 16384] fp32 -> f16 MFMA B-fragments. (unchanged)
// lane = q*16+ol holds B[k=c*32+q*8+jj][n=nt*16+ol]; Wws half8 idx = c*512+nt*64+lane.
// ---------------------------------------------------------------------------
__global__ __launch_bounds__(256) void wprep(const float* __restrict__ W,
                                             _Float16* __restrict__ Wws) {
    int t    = blockIdx.x * 256 + threadIdx.x;  // 0..262143 = 512 c * 8 nt * 64 lane
    int c    = t >> 9;
    int r    = t & 511;
    int nt   = r >> 6;
    int lane = r & 63;
    int q    = lane >> 4;
    int ol   = lane & 15;
    int o    = nt * 16 + ol;
    const float4t* src = (const float4t*)(W + (size_t)o * 16384 + c * 32 + q * 8);
    float4t a0 = src[0];
    float4t a1 = src[1];
    half8 h;
    h[0] = (_Float16)a0[0]; h[1] = (_Float16)a0[1];
    h[2] = (_Float16)a0[2]; h[3] = (_Float16)a0[3];
    h[4] = (_Float16)a1[0]; h[5] = (_Float16)a1[1];
    h[6] = (_Float16)a1[2]; h[7] = (_Float16)a1[3];
    *(half8*)(Wws + (size_t)t * 8) = h;
}

// ---------------------------------------------------------------------------
// Kernel 2: per (pair, 128-row m-block, 64-col n-half). Wave grid 2x2 =
// (wrow = m-half) x (kw = split-K j-pair): each wave computes 64 rows x 64
// cols over half of K (jc in {kw*2, kw*2+1}, all i). nt=4 -> one pk_mul per
// MFMA. Register budget for __launch_bounds__(256,3) (~168 unified/wave):
// acc 64 + W dbuf 32 (distance-1, NOT 3 buffers - R1 spilled) + x2f 16 +
// x1f 16 + 32-bit W offsets. W stream overshoots <=32 KB past Wws at the
// K tail: Wws is placed FIRST in ws so the overshoot lands in yws (values
// discarded) - no clamp select needed.
// ---------------------------------------------------------------------------
__global__ __launch_bounds__(256, 3) void gemm(const float* __restrict__ x,
                                               const _Float16* __restrict__ Wws,
                                               _Float16* __restrict__ yws,
                                               float* __restrict__ ssum,
                                               float* __restrict__ ssq) {
    __shared__ __align__(16) _Float16 x2t[128 * X2P];    // 34816 B: 128 rows x 128 j
    __shared__ __align__(16) _Float16 x1th[128 * X1P];   // 18432 B: 128 rows x 64 i

    int bid  = blockIdx.x;
    int p    = bid >> 7;
    int rem  = bid & 127;
    int mblk = rem >> 1;          // 64 m-blocks of 128 rows
    int nh   = rem & 1;
    int m0   = mblk * 128;
    int v1   = PAIR_A[p];
    int v2   = PAIR_B[p];
    int tid  = threadIdx.x;

    // ---- stage x2 tile (full 128x128, fp32 -> f16) ------------------------
    {
        const float4t* s2p = (const float4t*)(x + ((size_t)v2 * Bsz + m0) * Fdim);
        for (int it = 0; it < 16; ++it) {
            int idx = it * 256 + tid;
            int row = idx >> 5;
            int col = (idx & 31) * 4;
            float4t b = s2p[idx];
            half4t h2; h2[0]=(_Float16)b[0]; h2[1]=(_Float16)b[1];
                       h2[2]=(_Float16)b[2]; h2[3]=(_Float16)b[3];
            *(half4t*)&x2t[row * X2P + col] = h2;
        }
    }

    int lane  = tid & 63;
    int w     = tid >> 6;
    int wrow  = w >> 1;           // m-half: rows wrow*64 + mt*16 + ...
    int kw    = w & 1;            // split-K half: jc in {kw*2, kw*2+1}
    int ol    = lane & 15;
    int q     = lane >> 4;
    int rbase = wrow * 64;

    float4t acc[4][4];
#pragma unroll
    for (int mt = 0; mt < 4; ++mt)
#pragma unroll
        for (int nt = 0; nt < 4; ++nt)
            acc[mt][nt] = (float4t){0.f, 0.f, 0.f, 0.f};

    const half8* wb = (const half8*)Wws;
    const unsigned wlane = (unsigned)(nh * 256 + lane);   // half8 units
    const float* x1src = x + ((size_t)v1 * Bsz + m0) * Fdim;

    for (int kh = 0; kh < 2; ++kh) {
        if (kh) __syncthreads();      // all reads of previous x1 half done
        // ---- stage x1 half-tile: 128 rows x 64 i-cols ---------------------
        for (int it = 0; it < 8; ++it) {
            int idx = it * 256 + tid;
            int row = idx >> 4;
            int c4  = (idx & 15) * 4;
            float4t a = *(const float4t*)(x1src + (size_t)row * Fdim + kh * 64 + c4);
            half4t h1; h1[0]=(_Float16)a[0]; h1[1]=(_Float16)a[1];
                       h1[2]=(_Float16)a[2]; h1[3]=(_Float16)a[3];
            *(half4t*)&x1th[row * X1P + c4] = h1;
        }
        __syncthreads();

        for (int jcl = 0; jcl < 2; ++jcl) {
            int jc = kw * 2 + jcl;    // this wave's j-chunk (k-dim of MFMA)
            // x2 fragments: constant across the whole 64-i sweep of this jc
            half8 x2f[4];
#pragma unroll
            for (int mt = 0; mt < 4; ++mt)
                x2f[mt] = *(const half8*)&x2t[(rbase + mt * 16 + ol) * X2P + jc * 32 + q * 8];

            // W stream: chunk c = (kh*64+il)*4 + jc; half8 idx = c*512 + wlane
            // + nt*64. 32-bit index, uniform +=2048 per il -> saddr+voffset.
            unsigned woff = (unsigned)(kh * 256 + jc) * 512u + wlane;
            half8 bcur[4];
#pragma unroll
            for (int nt = 0; nt < 4; ++nt) bcur[nt] = wb[woff + nt * 64];
            woff += 2048;

            for (int il8 = 0; il8 < 8; ++il8) {
                half8 x1f[4];
#pragma unroll
                for (int mt = 0; mt < 4; ++mt)
                    x1f[mt] = *(const half8*)&x1th[(rbase + mt * 16 + ol) * X1P + il8 * 8];
#pragma unroll
                for (int ii = 0; ii < 8; ++ii) {
                    half8 bn[4];          // distance-1 prefetch (next il)
#pragma unroll
                    for (int nt = 0; nt < 4; ++nt)
                        bn[nt] = wb[woff + nt * 64];
#pragma unroll
                    for (int mt = 0; mt < 4; ++mt) {
                        _Float16 sc = x1f[mt][ii];
                        half8 a = x2f[mt] * sc;    // 4 pk_mul shared by 4 MFMAs
#pragma unroll
                        for (int nt = 0; nt < 4; ++nt)
                            acc[mt][nt] = __builtin_amdgcn_mfma_f32_16x16x32_f16(a, bcur[nt], acc[mt][nt], 0, 0, 0);
                    }
#pragma unroll
                    for (int nt = 0; nt < 4; ++nt) bcur[nt] = bn[nt];
                    woff += 2048;
                }
            }
        }
    }

    // ---- split-K combine (via x2t region, dead now) -----------------------
    __syncthreads();                  // everyone done reading x2t / x1th
    float4t* xch = (float4t*)x2t;     // 2 waves x 16 KB = 32 KB <= 34816 B
    if (kw == 1) {
#pragma unroll
        for (int mt = 0; mt < 4; ++mt)
#pragma unroll
            for (int nt = 0; nt < 4; ++nt)
                xch[wrow * 1024 + (mt * 4 + nt) * 64 + lane] = acc[mt][nt];
    }
    __syncthreads();
    if (kw == 0) {
#pragma unroll
        for (int mt = 0; mt < 4; ++mt)
#pragma unroll
            for (int nt = 0; nt < 4; ++nt)
                acc[mt][nt] += xch[wrow * 1024 + (mt * 4 + nt) * 64 + lane];

        // ---- epilogue: store y (f16) + per-o stats ------------------------
        float sum[4] = {0.f, 0.f, 0.f, 0.f};
        float sq[4]  = {0.f, 0.f, 0.f, 0.f};
#pragma unroll
        for (int mt = 0; mt < 4; ++mt) {
#pragma unroll
            for (int r = 0; r < 4; ++r) {
                size_t row = (size_t)p * Bsz + m0 + rbase + mt * 16 + q * 4 + r;
#pragma unroll
                for (int nt = 0; nt < 4; ++nt) {
                    float v = acc[mt][nt][r];
                    sum[nt] += v; sq[nt] += v * v;
                    yws[row * Fdim + nh * 64 + nt * 16 + ol] = (_Float16)v;
                }
            }
        }
#pragma unroll
        for (int nt = 0; nt < 4; ++nt) {
            sum[nt] += __shfl_xor(sum[nt], 16, 64);  sum[nt] += __shfl_xor(sum[nt], 32, 64);
            sq[nt]  += __shfl_xor(sq[nt], 16, 64);   sq[nt]  += __shfl_xor(sq[nt], 32, 64);
        }
        if (q == 0) {
#pragma unroll
            for (int nt = 0; nt < 4; ++nt) {
                atomicAdd(&ssum[p * Fdim + nh * 64 + nt * 16 + ol], sum[nt]);
                atomicAdd(&ssq [p * Fdim + nh * 64 + nt * 16 + ol], sq[nt]);
            }
        }
    }
}

// ---------------------------------------------------------------------------
// Kernel 3: BN (train-mode batch stats, biased var) + ReLU, f16 y -> fp32 out.
// ---------------------------------------------------------------------------
__global__ __launch_bounds__(256) void bnrelu(const _Float16* __restrict__ yws,
                                              const float* __restrict__ ssum,
                                              const float* __restrict__ ssq,
                                              const float* __restrict__ gamma,
                                              const float* __restrict__ beta,
                                              float* __restrict__ out) {
    __shared__ float gs[128], sh[128];
    size_t ebase = (size_t)blockIdx.x * 1024;
    int p = (int)(ebase >> 20);            // B*F = 2^20
    int t = threadIdx.x;
    if (t < 128) {
        float mean = ssum[p * Fdim + t] * (1.0f / 8192.0f);
        float var  = ssq [p * Fdim + t] * (1.0f / 8192.0f) - mean * mean;
        float g    = gamma[t] * rsqrtf(var + EPSI);
        gs[t] = g;
        sh[t] = beta[t] - g * mean;
    }
    __syncthreads();
    size_t e0 = ebase + (size_t)t * 4;
    int o0 = (int)(e0 & 127);
    half4t y = *(const half4t*)(yws + e0);
    float4t r;
#pragma unroll
    for (int l = 0; l < 4; ++l) {
        float v = fmaf(gs[o0 + l], (float)y[l], sh[o0 + l]);
        r[l] = v > 0.f ? v : 0.f;
    }
    *(float4t*)(out + e0) = r;
}

// ---------------------------------------------------------------------------
extern "C" void kernel_launch(void* const* d_in, const int* in_sizes, int n_in,
                              void* d_out, int out_size, void* d_ws, size_t ws_size,
                              hipStream_t stream) {
    const float* x     = (const float*)d_in[0];
    const float* W     = (const float*)d_in[1];
    // d_in[2] = linear bias b: mathematically cancelled by train-mode BN.
    const float* gamma = (const float*)d_in[3];
    const float* beta  = (const float*)d_in[4];
    float* out = (float*)d_out;

    // Layout: Wws FIRST so the W-stream's <=32 KB K-tail overshoot lands in
    // yws (allocated, values discarded) instead of past the workspace.
    char* ws = (char*)d_ws;
    _Float16* Wws = (_Float16*)ws;                       // 128*16384*2  =  4,194,304 B
    _Float16* yws = (_Float16*)(ws + 4194304);           // 6*8192*128*2 = 12,582,912 B
    float*    ssum = (float*)(ws + 16777216);            // 768 floats
    float*    ssq  = ssum + Pn * Fdim;                   // 768 floats

    (void)hipMemsetAsync(ssum, 0, 2 * Pn * Fdim * sizeof(float), stream);
    wprep<<<1024, 256, 0, stream>>>(W, Wws);
    gemm<<<768, 256, 0, stream>>>(x, Wws, yws, ssum, ssq);
    bnrelu<<<6144, 256, 0, stream>>>(yws, ssum, ssq, gamma, beta, out);
}

// Round 3
// 308.962 us; speedup vs baseline: 2.6352x; 1.5710x over previous
//
#include <hip/hip_runtime.h>

#define Fdim 128
#define Bsz  8192
#define Pn   6
#define EPSI 1e-5f
#define X2P 136       // x2 tile pitch (halves): 272 B rows, 2-way bank max (free)
#define X1P 72        // x1 half-tile pitch: 144 B rows -> 2-way max on ds_read_b128

typedef _Float16 half8  __attribute__((ext_vector_type(8)));
typedef _Float16 half4t __attribute__((ext_vector_type(4)));
typedef float    float4t __attribute__((ext_vector_type(4)));

__constant__ int PAIR_A[6] = {0,0,0,1,1,2};
__constant__ int PAIR_B[6] = {1,2,3,2,3,3};

// ---------------------------------------------------------------------------
// Kernel 1: W [128 x 16384] fp32 -> f16 MFMA B-fragments. (unchanged)
// lane = q*16+ol holds B[k=c*32+q*8+jj][n=nt*16+ol]; Wws half8 idx = c*512+nt*64+lane.
// ---------------------------------------------------------------------------
__global__ __launch_bounds__(256) void wprep(const float* __restrict__ W,
                                             _Float16* __restrict__ Wws) {
    int t    = blockIdx.x * 256 + threadIdx.x;  // 0..262143 = 512 c * 8 nt * 64 lane
    int c    = t >> 9;
    int r    = t & 511;
    int nt   = r >> 6;
    int lane = r & 63;
    int q    = lane >> 4;
    int ol   = lane & 15;
    int o    = nt * 16 + ol;
    const float4t* src = (const float4t*)(W + (size_t)o * 16384 + c * 32 + q * 8);
    float4t a0 = src[0];
    float4t a1 = src[1];
    half8 h;
    h[0] = (_Float16)a0[0]; h[1] = (_Float16)a0[1];
    h[2] = (_Float16)a0[2]; h[3] = (_Float16)a0[3];
    h[4] = (_Float16)a1[0]; h[5] = (_Float16)a1[1];
    h[6] = (_Float16)a1[2]; h[7] = (_Float16)a1[3];
    *(half8*)(Wws + (size_t)t * 8) = h;
}

// ---------------------------------------------------------------------------
// Kernel 2: per (pair, 128-row m-block, 64-col n-half). Wave grid 2x2 =
// (wrow = m-half) x (kw = split-K j-pair). nt=4 -> one pk_mul per MFMA.
// R1/R2 spilled (~200-830 MB scratch traffic): the scheduler hoisted
// prefetch sets past the (256,3) ~168-reg cap. Containment here:
//   - sched_barrier(0) at the end of every ii body (no cross-ii hoisting;
//     live W regs bounded at 32). Distance-1 prefetch still gives a full
//     ~310-cyc MFMA window of lead (> L2 ~200 cyc).
//   - parity-rotated wbuf[2][4] (compile-time indices, no rotation copies).
//   - #pragma unroll 1 on il8 (no 8x body replication).
// True live set: acc 64 + wbuf 32 + x2f 16 + x1f 16 + addr ~10 = ~140.
// W stream overshoots <=70 KB past Wws at the K tail: Wws is FIRST in ws so
// the overshoot lands in yws (values discarded).
// ---------------------------------------------------------------------------
__global__ __launch_bounds__(256, 3) void gemm(const float* __restrict__ x,
                                               const _Float16* __restrict__ Wws,
                                               _Float16* __restrict__ yws,
                                               float* __restrict__ ssum,
                                               float* __restrict__ ssq) {
    __shared__ __align__(16) _Float16 x2t[128 * X2P];    // 34816 B: 128 rows x 128 j
    __shared__ __align__(16) _Float16 x1th[128 * X1P];   // 18432 B: 128 rows x 64 i

    int bid  = blockIdx.x;
    int p    = bid >> 7;
    int rem  = bid & 127;
    int mblk = rem >> 1;          // 64 m-blocks of 128 rows
    int nh   = rem & 1;
    int m0   = mblk * 128;
    int v1   = PAIR_A[p];
    int v2   = PAIR_B[p];
    int tid  = threadIdx.x;

    // ---- stage x2 tile (full 128x128, fp32 -> f16) ------------------------
    {
        const float4t* s2p = (const float4t*)(x + ((size_t)v2 * Bsz + m0) * Fdim);
        for (int it = 0; it < 16; ++it) {
            int idx = it * 256 + tid;
            int row = idx >> 5;
            int col = (idx & 31) * 4;
            float4t b = s2p[idx];
            half4t h2; h2[0]=(_Float16)b[0]; h2[1]=(_Float16)b[1];
                       h2[2]=(_Float16)b[2]; h2[3]=(_Float16)b[3];
            *(half4t*)&x2t[row * X2P + col] = h2;
        }
    }

    int lane  = tid & 63;
    int w     = tid >> 6;
    int wrow  = w >> 1;           // m-half: rows wrow*64 + mt*16 + ...
    int kw    = w & 1;            // split-K half: jc in {kw*2, kw*2+1}
    int ol    = lane & 15;
    int q     = lane >> 4;
    int rbase = wrow * 64;

    float4t acc[4][4];
#pragma unroll
    for (int mt = 0; mt < 4; ++mt)
#pragma unroll
        for (int nt = 0; nt < 4; ++nt)
            acc[mt][nt] = (float4t){0.f, 0.f, 0.f, 0.f};

    const half8* wb = (const half8*)Wws;
    const unsigned wlane = (unsigned)(nh * 256 + lane);   // half8 units
    const float* x1src = x + ((size_t)v1 * Bsz + m0) * Fdim;

    for (int kh = 0; kh < 2; ++kh) {
        if (kh) __syncthreads();      // all reads of previous x1 half done
        // ---- stage x1 half-tile: 128 rows x 64 i-cols ---------------------
        for (int it = 0; it < 8; ++it) {
            int idx = it * 256 + tid;
            int row = idx >> 4;
            int c4  = (idx & 15) * 4;
            float4t a = *(const float4t*)(x1src + (size_t)row * Fdim + kh * 64 + c4);
            half4t h1; h1[0]=(_Float16)a[0]; h1[1]=(_Float16)a[1];
                       h1[2]=(_Float16)a[2]; h1[3]=(_Float16)a[3];
            *(half4t*)&x1th[row * X1P + c4] = h1;
        }
        __syncthreads();

        for (int jcl = 0; jcl < 2; ++jcl) {
            int jc = kw * 2 + jcl;    // this wave's j-chunk (k-dim of MFMA)
            // x2 fragments: constant across the whole 64-i sweep of this jc
            half8 x2f[4];
#pragma unroll
            for (int mt = 0; mt < 4; ++mt)
                x2f[mt] = *(const half8*)&x2t[(rbase + mt * 16 + ol) * X2P + jc * 32 + q * 8];

            // W stream: chunk c = (kh*64+il)*4 + jc; half8 idx = c*512 + wlane
            // + nt*64. 32-bit index, uniform +=2048 per il -> saddr+voffset.
            unsigned woff = (unsigned)(kh * 256 + jc) * 512u + wlane;
            half8 wbuf[2][4];
#pragma unroll
            for (int nt = 0; nt < 4; ++nt) wbuf[0][nt] = wb[woff + nt * 64];
            woff += 2048;

#pragma unroll 1
            for (int il8 = 0; il8 < 8; ++il8) {
                half8 x1f[4];
#pragma unroll
                for (int mt = 0; mt < 4; ++mt)
                    x1f[mt] = *(const half8*)&x1th[(rbase + mt * 16 + ol) * X1P + il8 * 8];
#pragma unroll
                for (int ii = 0; ii < 8; ++ii) {
                    const int cur = ii & 1;
                    const int nxt = cur ^ 1;
                    // distance-1 prefetch of the next il chunk (parity slot)
#pragma unroll
                    for (int nt = 0; nt < 4; ++nt)
                        wbuf[nxt][nt] = wb[woff + nt * 64];
#pragma unroll
                    for (int mt = 0; mt < 4; ++mt) {
                        _Float16 sc = x1f[mt][ii];
                        half8 a = x2f[mt] * sc;    // 4 pk_mul shared by 4 MFMAs
#pragma unroll
                        for (int nt = 0; nt < 4; ++nt)
                            acc[mt][nt] = __builtin_amdgcn_mfma_f32_16x16x32_f16(a, wbuf[cur][nt], acc[mt][nt], 0, 0, 0);
                    }
                    woff += 2048;
                    __builtin_amdgcn_sched_barrier(0);   // no cross-ii hoisting
                }
            }
        }
    }

    // ---- split-K combine (via x2t region, dead now) -----------------------
    __syncthreads();                  // everyone done reading x2t / x1th
    float4t* xch = (float4t*)x2t;     // 2 waves x 16 KB = 32 KB <= 34816 B
    if (kw == 1) {
#pragma unroll
        for (int mt = 0; mt < 4; ++mt)
#pragma unroll
            for (int nt = 0; nt < 4; ++nt)
                xch[wrow * 1024 + (mt * 4 + nt) * 64 + lane] = acc[mt][nt];
    }
    __syncthreads();
    if (kw == 0) {
#pragma unroll
        for (int mt = 0; mt < 4; ++mt)
#pragma unroll
            for (int nt = 0; nt < 4; ++nt)
                acc[mt][nt] += xch[wrow * 1024 + (mt * 4 + nt) * 64 + lane];

        // ---- epilogue: store y (f16) + per-o stats ------------------------
        float sum[4] = {0.f, 0.f, 0.f, 0.f};
        float sq[4]  = {0.f, 0.f, 0.f, 0.f};
#pragma unroll
        for (int mt = 0; mt < 4; ++mt) {
#pragma unroll
            for (int r = 0; r < 4; ++r) {
                size_t row = (size_t)p * Bsz + m0 + rbase + mt * 16 + q * 4 + r;
#pragma unroll
                for (int nt = 0; nt < 4; ++nt) {
                    float v = acc[mt][nt][r];
                    sum[nt] += v; sq[nt] += v * v;
                    yws[row * Fdim + nh * 64 + nt * 16 + ol] = (_Float16)v;
                }
            }
        }
#pragma unroll
        for (int nt = 0; nt < 4; ++nt) {
            sum[nt] += __shfl_xor(sum[nt], 16, 64);  sum[nt] += __shfl_xor(sum[nt], 32, 64);
            sq[nt]  += __shfl_xor(sq[nt], 16, 64);   sq[nt]  += __shfl_xor(sq[nt], 32, 64);
        }
        if (q == 0) {
#pragma unroll
            for (int nt = 0; nt < 4; ++nt) {
                atomicAdd(&ssum[p * Fdim + nh * 64 + nt * 16 + ol], sum[nt]);
                atomicAdd(&ssq [p * Fdim + nh * 64 + nt * 16 + ol], sq[nt]);
            }
        }
    }
}

// ---------------------------------------------------------------------------
// Kernel 3: BN (train-mode batch stats, biased var) + ReLU, f16 y -> fp32 out.
// ---------------------------------------------------------------------------
__global__ __launch_bounds__(256) void bnrelu(const _Float16* __restrict__ yws,
                                              const float* __restrict__ ssum,
                                              const float* __restrict__ ssq,
                                              const float* __restrict__ gamma,
                                              const float* __restrict__ beta,
                                              float* __restrict__ out) {
    __shared__ float gs[128], sh[128];
    size_t ebase = (size_t)blockIdx.x * 1024;
    int p = (int)(ebase >> 20);            // B*F = 2^20
    int t = threadIdx.x;
    if (t < 128) {
        float mean = ssum[p * Fdim + t] * (1.0f / 8192.0f);
        float var  = ssq [p * Fdim + t] * (1.0f / 8192.0f) - mean * mean;
        float g    = gamma[t] * rsqrtf(var + EPSI);
        gs[t] = g;
        sh[t] = beta[t] - g * mean;
    }
    __syncthreads();
    size_t e0 = ebase + (size_t)t * 4;
    int o0 = (int)(e0 & 127);
    half4t y = *(const half4t*)(yws + e0);
    float4t r;
#pragma unroll
    for (int l = 0; l < 4; ++l) {
        float v = fmaf(gs[o0 + l], (float)y[l], sh[o0 + l]);
        r[l] = v > 0.f ? v : 0.f;
    }
    *(float4t*)(out + e0) = r;
}

// ---------------------------------------------------------------------------
extern "C" void kernel_launch(void* const* d_in, const int* in_sizes, int n_in,
                              void* d_out, int out_size, void* d_ws, size_t ws_size,
                              hipStream_t stream) {
    const float* x     = (const float*)d_in[0];
    const float* W     = (const float*)d_in[1];
    // d_in[2] = linear bias b: mathematically cancelled by train-mode BN.
    const float* gamma = (const float*)d_in[3];
    const float* beta  = (const float*)d_in[4];
    float* out = (float*)d_out;

    // Layout: Wws FIRST so the W-stream's <=70 KB K-tail overshoot lands in
    // yws (allocated, values discarded) instead of past the workspace.
    char* ws = (char*)d_ws;
    _Float16* Wws = (_Float16*)ws;                       // 128*16384*2  =  4,194,304 B
    _Float16* yws = (_Float16*)(ws + 4194304);           // 6*8192*128*2 = 12,582,912 B
    float*    ssum = (float*)(ws + 16777216);            // 768 floats
    float*    ssq  = ssum + Pn * Fdim;                   // 768 floats

    (void)hipMemsetAsync(ssum, 0, 2 * Pn * Fdim * sizeof(float), stream);
    wprep<<<1024, 256, 0, stream>>>(W, Wws);
    gemm<<<768, 256, 0, stream>>>(x, Wws, yws, ssum, ssq);
    bnrelu<<<6144, 256, 0, stream>>>(yws, ssum, ssq, gamma, beta, out);
}

// Round 4
// 287.672 us; speedup vs baseline: 2.8302x; 1.0740x over previous
//
#include <hip/hip_runtime.h>

#define Fdim 128
#define Bsz  8192
#define Pn   6
#define EPSI 1e-5f
#define X2P 130       // x2 pitch: 65-dword rows (odd) -> conflict-free 32-row b128 reads
#define X1P 66        // x1 pitch: 33-dword rows (odd) -> conflict-free 32-row b128 reads

typedef _Float16 half8   __attribute__((ext_vector_type(8)));
typedef _Float16 half4t  __attribute__((ext_vector_type(4)));
typedef float    float4t __attribute__((ext_vector_type(4)));
typedef float    float16t __attribute__((ext_vector_type(16)));

__constant__ int PAIR_A[6] = {0,0,0,1,1,2};
__constant__ int PAIR_B[6] = {1,2,3,2,3,3};

// ---------------------------------------------------------------------------
// Kernel 1: W [128 x 16384] fp32 -> f16 32x32x16 B-fragments.
// B[k][n] layout per MFMA: n = lane&31, k = (lane>>5)*8 + e (16-k chunk).
// Stream layout: frag f = ntile*1024 + jc16*128 + i  (ntile = 32-col group,
// jc16 = 16-j chunk, i = outer-product index). Each wave in gemm streams its
// ntile's frags sequentially (1 KB/frag). Wws element (f*64+lane)*8+e holds
// W[n = ntile*32 + (lane&31)][k = i*128 + jc16*16 + (lane>>5)*8 + e].
// ---------------------------------------------------------------------------
__global__ __launch_bounds__(256) void wprep(const float* __restrict__ W,
                                             _Float16* __restrict__ Wws) {
    int t    = blockIdx.x * 256 + threadIdx.x;  // 0..262143 = 4096 frags * 64 lanes
    int f    = t >> 6;
    int lane = t & 63;
    int ntile = f >> 10;
    int jc    = (f >> 7) & 7;
    int i     = f & 127;
    int q1 = lane >> 5;
    int nn = lane & 31;
    int n  = ntile * 32 + nn;
    int k0 = i * 128 + jc * 16 + q1 * 8;
    const float4t* src = (const float4t*)(W + (size_t)n * 16384 + k0);
    float4t a0 = src[0];
    float4t a1 = src[1];
    half8 h;
    h[0] = (_Float16)a0[0]; h[1] = (_Float16)a0[1];
    h[2] = (_Float16)a0[2]; h[3] = (_Float16)a0[3];
    h[4] = (_Float16)a1[0]; h[5] = (_Float16)a1[1];
    h[6] = (_Float16)a1[2]; h[7] = (_Float16)a1[3];
    *(half8*)(Wws + (size_t)t * 8) = h;
}

// ---------------------------------------------------------------------------
// Kernel 2: 32x32x16 MFMA version. Block = (pair, 128-row m-block, 64-col
// n-half); wave grid 2x2 = (wrow: 64-row half) x (wcol: 32-col tile). Per
// wave: mt=2 m-tiles of 32 rows, one n-tile -> acc 2x16 = 32 regs. A-frag
// built on the fly: a[m=lane&31][k=q1*8+e] = x2[m, jc*16+q1*8+e] * x1[m, i]
// -> 4 pk_mul per mt shared by... per i-step: 8 pk (16cy) vs 2 MFMA (64.6cy
// SIMD) = 28% VALU (R0-R3 structure was 60-80%+spill). Live set ~80 regs:
// no spill under (256,3). W dist-4 ring prefetch; stream overshoots <=5 KB
// past Wws at the very end -> Wws FIRST in ws, overshoot lands in yws.
// ---------------------------------------------------------------------------
__global__ __launch_bounds__(256, 3) void gemm(const float* __restrict__ x,
                                               const _Float16* __restrict__ Wws,
                                               _Float16* __restrict__ yws,
                                               float* __restrict__ ssum,
                                               float* __restrict__ ssq) {
    __shared__ __align__(16) _Float16 x2t[128 * X2P];    // 33280 B: 128 rows x 128 j
    __shared__ __align__(16) _Float16 x1th[128 * X1P];   // 16896 B: 128 rows x 64 i

    int bid  = blockIdx.x;
    int p    = bid >> 7;
    int rem  = bid & 127;
    int mblk = rem >> 1;          // 64 m-blocks of 128 rows
    int nh   = rem & 1;
    int m0   = mblk * 128;
    int v1   = PAIR_A[p];
    int v2   = PAIR_B[p];
    int tid  = threadIdx.x;

    // ---- stage x2 tile (full 128x128, fp32 -> f16) ------------------------
    {
        const float4t* s2p = (const float4t*)(x + ((size_t)v2 * Bsz + m0) * Fdim);
        for (int it = 0; it < 16; ++it) {
            int idx = it * 256 + tid;
            int row = idx >> 5;
            int col = (idx & 31) * 4;
            float4t b = s2p[idx];
            half4t h2; h2[0]=(_Float16)b[0]; h2[1]=(_Float16)b[1];
                       h2[2]=(_Float16)b[2]; h2[3]=(_Float16)b[3];
            *(half4t*)&x2t[row * X2P + col] = h2;
        }
    }

    int lane  = tid & 63;
    int w     = tid >> 6;
    int wrow  = w >> 1;           // 64-row half
    int wcol  = w & 1;            // 32-col tile within the n-half
    int nn    = lane & 31;
    int q1    = lane >> 5;
    int ntile = nh * 2 + wcol;    // global 32-col tile 0..3
    int rbase = wrow * 64;

    float16t acc[2];
#pragma unroll
    for (int mt = 0; mt < 2; ++mt)
#pragma unroll
        for (int e = 0; e < 16; ++e)
            acc[mt][e] = 0.f;

    const half8* wb = (const half8*)Wws;
    const float* x1src = x + ((size_t)v1 * Bsz + m0) * Fdim;

    for (int kh = 0; kh < 2; ++kh) {
        if (kh) __syncthreads();      // all reads of previous x1 half done
        // ---- stage x1 half-tile: 128 rows x 64 i-cols ---------------------
        for (int it = 0; it < 8; ++it) {
            int idx = it * 256 + tid;
            int row = idx >> 4;
            int c4  = (idx & 15) * 4;
            float4t a = *(const float4t*)(x1src + (size_t)row * Fdim + kh * 64 + c4);
            half4t h1; h1[0]=(_Float16)a[0]; h1[1]=(_Float16)a[1];
                       h1[2]=(_Float16)a[2]; h1[3]=(_Float16)a[3];
            *(half4t*)&x1th[row * X1P + c4] = h1;
        }
        __syncthreads();

#pragma unroll 1
        for (int jc = 0; jc < 8; ++jc) {
            // x2 fragments: constant across the whole i-sweep of this jc
            half8 x2f[2];
#pragma unroll
            for (int mt = 0; mt < 2; ++mt)
                x2f[mt] = *(const half8*)&x2t[(rbase + mt * 32 + nn) * X2P + jc * 16 + q1 * 8];

            // W stream: frag f = ntile*1024 + jc*128 + kh*64 + il, sequential
            // in il. half8 idx = f*64 + lane. Dist-4 ring prefetch (16 regs).
            unsigned woff = (unsigned)((ntile * 1024 + jc * 128 + kh * 64) * 64 + lane);
            half8 wbuf[4];
#pragma unroll
            for (int d = 0; d < 4; ++d) wbuf[d] = wb[woff + d * 64];

#pragma unroll
            for (int il8 = 0; il8 < 8; ++il8) {
                half8 x1f[2];
#pragma unroll
                for (int mt = 0; mt < 2; ++mt)
                    x1f[mt] = *(const half8*)&x1th[(rbase + mt * 32 + nn) * X1P + il8 * 8];
#pragma unroll
                for (int ii = 0; ii < 8; ++ii) {
                    const int il = il8 * 8 + ii;
                    half8 a0 = x2f[0] * x1f[0][ii];
                    half8 a1 = x2f[1] * x1f[1][ii];
                    acc[0] = __builtin_amdgcn_mfma_f32_32x32x16_f16(a0, wbuf[il & 3], acc[0], 0, 0, 0);
                    acc[1] = __builtin_amdgcn_mfma_f32_32x32x16_f16(a1, wbuf[il & 3], acc[1], 0, 0, 0);
                    wbuf[il & 3] = wb[woff + (unsigned)(il + 4) * 64];
                }
                __builtin_amdgcn_sched_barrier(0);   // bound hoist window (spill insurance)
            }
        }
    }

    // ---- epilogue: store y (f16) + per-o stats ----------------------------
    // C/D 32x32 layout: col = lane&31, row = (r&3) + 8*(r>>2) + 4*q1.
    float sum = 0.f, sq = 0.f;
    int colg = ntile * 32 + nn;
#pragma unroll
    for (int mt = 0; mt < 2; ++mt) {
#pragma unroll
        for (int r = 0; r < 16; ++r) {
            int rl = (r & 3) + 8 * (r >> 2) + 4 * q1;
            size_t row = (size_t)p * Bsz + m0 + rbase + mt * 32 + rl;
            float v = acc[mt][r];
            sum += v; sq += v * v;
            yws[row * Fdim + colg] = (_Float16)v;
        }
    }
    sum += __shfl_xor(sum, 32, 64);
    sq  += __shfl_xor(sq, 32, 64);
    if (q1 == 0) {
        atomicAdd(&ssum[p * Fdim + colg], sum);
        atomicAdd(&ssq [p * Fdim + colg], sq);
    }
}

// ---------------------------------------------------------------------------
// Kernel 3: BN (train-mode batch stats, biased var) + ReLU, f16 y -> fp32 out.
// ---------------------------------------------------------------------------
__global__ __launch_bounds__(256) void bnrelu(const _Float16* __restrict__ yws,
                                              const float* __restrict__ ssum,
                                              const float* __restrict__ ssq,
                                              const float* __restrict__ gamma,
                                              const float* __restrict__ beta,
                                              float* __restrict__ out) {
    __shared__ float gs[128], sh[128];
    size_t ebase = (size_t)blockIdx.x * 1024;
    int p = (int)(ebase >> 20);            // B*F = 2^20
    int t = threadIdx.x;
    if (t < 128) {
        float mean = ssum[p * Fdim + t] * (1.0f / 8192.0f);
        float var  = ssq [p * Fdim + t] * (1.0f / 8192.0f) - mean * mean;
        float g    = gamma[t] * rsqrtf(var + EPSI);
        gs[t] = g;
        sh[t] = beta[t] - g * mean;
    }
    __syncthreads();
    size_t e0 = ebase + (size_t)t * 4;
    int o0 = (int)(e0 & 127);
    half4t y = *(const half4t*)(yws + e0);
    float4t r;
#pragma unroll
    for (int l = 0; l < 4; ++l) {
        float v = fmaf(gs[o0 + l], (float)y[l], sh[o0 + l]);
        r[l] = v > 0.f ? v : 0.f;
    }
    *(float4t*)(out + e0) = r;
}

// ---------------------------------------------------------------------------
extern "C" void kernel_launch(void* const* d_in, const int* in_sizes, int n_in,
                              void* d_out, int out_size, void* d_ws, size_t ws_size,
                              hipStream_t stream) {
    const float* x     = (const float*)d_in[0];
    const float* W     = (const float*)d_in[1];
    // d_in[2] = linear bias b: mathematically cancelled by train-mode BN.
    const float* gamma = (const float*)d_in[3];
    const float* beta  = (const float*)d_in[4];
    float* out = (float*)d_out;

    // Layout: Wws FIRST so the W-stream's <=5 KB K-tail overshoot lands in
    // yws (allocated, values discarded) instead of past the workspace.
    char* ws = (char*)d_ws;
    _Float16* Wws = (_Float16*)ws;                       // 128*16384*2  =  4,194,304 B
    _Float16* yws = (_Float16*)(ws + 4194304);           // 6*8192*128*2 = 12,582,912 B
    float*    ssum = (float*)(ws + 16777216);            // 768 floats
    float*    ssq  = ssum + Pn * Fdim;                   // 768 floats

    (void)hipMemsetAsync(ssum, 0, 2 * Pn * Fdim * sizeof(float), stream);
    wprep<<<1024, 256, 0, stream>>>(W, Wws);
    gemm<<<768, 256, 0, stream>>>(x, Wws, yws, ssum, ssq);
    bnrelu<<<6144, 256, 0, stream>>>(yws, ssum, ssq, gamma, beta, out);
}

// Round 5
// 270.936 us; speedup vs baseline: 3.0050x; 1.0618x over previous
//
#include <hip/hip_runtime.h>

#define Fdim 128
#define Bsz  8192
#define Pn   6
#define EPSI 1e-5f
#define X2P 130       // x2 pitch: 65-dword rows (odd) -> conflict-free 32-row b128 reads
#define X1P 66        // x1 pitch: 33-dword rows (odd) -> conflict-free 32-row b128 reads

typedef _Float16 half8   __attribute__((ext_vector_type(8)));
typedef _Float16 half4t  __attribute__((ext_vector_type(4)));
typedef float    float4t __attribute__((ext_vector_type(4)));
typedef float    float16t __attribute__((ext_vector_type(16)));

__constant__ int PAIR_A[6] = {0,0,0,1,1,2};
__constant__ int PAIR_B[6] = {1,2,3,2,3,3};

// ---------------------------------------------------------------------------
// Kernel 1: W [128 x 16384] fp32 -> f16 32x32x16 B-fragments. (unchanged)
// Frag f = ntile*1024 + jc16*128 + i; element (f*64+lane)*8+e holds
// W[n = ntile*32 + (lane&31)][k = i*128 + jc16*16 + (lane>>5)*8 + e].
// ---------------------------------------------------------------------------
__global__ __launch_bounds__(256) void wprep(const float* __restrict__ W,
                                             _Float16* __restrict__ Wws) {
    int t    = blockIdx.x * 256 + threadIdx.x;  // 0..262143 = 4096 frags * 64 lanes
    int f    = t >> 6;
    int lane = t & 63;
    int ntile = f >> 10;
    int jc    = (f >> 7) & 7;
    int i     = f & 127;
    int q1 = lane >> 5;
    int nn = lane & 31;
    int n  = ntile * 32 + nn;
    int k0 = i * 128 + jc * 16 + q1 * 8;
    const float4t* src = (const float4t*)(W + (size_t)n * 16384 + k0);
    float4t a0 = src[0];
    float4t a1 = src[1];
    half8 h;
    h[0] = (_Float16)a0[0]; h[1] = (_Float16)a0[1];
    h[2] = (_Float16)a0[2]; h[3] = (_Float16)a0[3];
    h[4] = (_Float16)a1[0]; h[5] = (_Float16)a1[1];
    h[6] = (_Float16)a1[2]; h[7] = (_Float16)a1[3];
    *(half8*)(Wws + (size_t)t * 8) = h;
}

// ---------------------------------------------------------------------------
// Kernel 2: 32x32x16, W-reuse x4. R4 post-mortem: R0 and R4 both plateau at
// ~15 TB/s W-stream (64 FLOP per W-byte needs 39 TB/s at full MFMA rate >
// 34.5 TB/s L2 ceiling) -> W bandwidth is the wall. Here each wave covers
// ALL 128 rows (mt=4 of 32): one 1 KB W frag feeds 4 MFMAs = 128 FLOP/B,
// halving W demand (~19.5 TB/s at full rate, under the ceiling).
// Wave grid 2x2 = (wcol: 32-col tile) x (kw: split-K j-half, jc 0-3 / 4-7);
// partials combined via LDS (x2t region, dead post-loop); kw=0 waves do the
// epilogue. Grid stays 768 = 3 blocks/CU, one clean round.
// Regs: acc 64 + x2f 16 + x1f 16 + wbuf 16 + addr ~15 = ~130 < 168 cap,
// guarded by R4's proven containment (unroll-1 jcl, parity ring,
// sched_barrier per il8). W stream overshoots <=4 KB past Wws at the tail:
// Wws FIRST in ws -> lands in yws (values discarded).
// ---------------------------------------------------------------------------
__global__ __launch_bounds__(256, 3) void gemm(const float* __restrict__ x,
                                               const _Float16* __restrict__ Wws,
                                               _Float16* __restrict__ yws,
                                               float* __restrict__ ssum,
                                               float* __restrict__ ssq) {
    __shared__ __align__(16) _Float16 x2t[128 * X2P];    // 33280 B: 128 rows x 128 j
    __shared__ __align__(16) _Float16 x1th[128 * X1P];   // 16896 B: 128 rows x 64 i

    int bid  = blockIdx.x;
    int p    = bid >> 7;
    int rem  = bid & 127;
    int mblk = rem >> 1;          // 64 m-blocks of 128 rows
    int nh   = rem & 1;
    int m0   = mblk * 128;
    int v1   = PAIR_A[p];
    int v2   = PAIR_B[p];
    int tid  = threadIdx.x;

    // ---- stage x2 tile (full 128x128, fp32 -> f16) ------------------------
    {
        const float4t* s2p = (const float4t*)(x + ((size_t)v2 * Bsz + m0) * Fdim);
        for (int it = 0; it < 16; ++it) {
            int idx = it * 256 + tid;
            int row = idx >> 5;
            int col = (idx & 31) * 4;
            float4t b = s2p[idx];
            half4t h2; h2[0]=(_Float16)b[0]; h2[1]=(_Float16)b[1];
                       h2[2]=(_Float16)b[2]; h2[3]=(_Float16)b[3];
            *(half4t*)&x2t[row * X2P + col] = h2;
        }
    }

    int lane  = tid & 63;
    int w     = tid >> 6;
    int wcol  = w & 1;            // 32-col tile within the n-half
    int kw    = w >> 1;           // split-K j-half: jc in {kw*4 .. kw*4+3}
    int nn    = lane & 31;
    int q1    = lane >> 5;
    int ntile = nh * 2 + wcol;    // global 32-col tile 0..3

    float16t acc[4];
#pragma unroll
    for (int mt = 0; mt < 4; ++mt)
#pragma unroll
        for (int e = 0; e < 16; ++e)
            acc[mt][e] = 0.f;

    const half8* wb = (const half8*)Wws;
    const float* x1src = x + ((size_t)v1 * Bsz + m0) * Fdim;

    for (int kh = 0; kh < 2; ++kh) {
        if (kh) __syncthreads();      // all reads of previous x1 half done
        // ---- stage x1 half-tile: 128 rows x 64 i-cols ---------------------
        for (int it = 0; it < 8; ++it) {
            int idx = it * 256 + tid;
            int row = idx >> 4;
            int c4  = (idx & 15) * 4;
            float4t a = *(const float4t*)(x1src + (size_t)row * Fdim + kh * 64 + c4);
            half4t h1; h1[0]=(_Float16)a[0]; h1[1]=(_Float16)a[1];
                       h1[2]=(_Float16)a[2]; h1[3]=(_Float16)a[3];
            *(half4t*)&x1th[row * X1P + c4] = h1;
        }
        __syncthreads();

#pragma unroll 1
        for (int jcl = 0; jcl < 4; ++jcl) {
            int jc = kw * 4 + jcl;    // this wave's 16-j chunk
            // x2 fragments: constant across the whole i-sweep of this jc
            half8 x2f[4];
#pragma unroll
            for (int mt = 0; mt < 4; ++mt)
                x2f[mt] = *(const half8*)&x2t[(mt * 32 + nn) * X2P + jc * 16 + q1 * 8];

            // W stream: frag f = ntile*1024 + jc*128 + kh*64 + il, sequential
            // in il. half8 idx = f*64 + lane. Dist-4 ring prefetch (16 regs).
            unsigned woff = (unsigned)((ntile * 1024 + jc * 128 + kh * 64) * 64 + lane);
            half8 wbuf[4];
#pragma unroll
            for (int d = 0; d < 4; ++d) wbuf[d] = wb[woff + d * 64];

#pragma unroll
            for (int il8 = 0; il8 < 8; ++il8) {
                half8 x1f[4];
#pragma unroll
                for (int mt = 0; mt < 4; ++mt)
                    x1f[mt] = *(const half8*)&x1th[(mt * 32 + nn) * X1P + il8 * 8];
#pragma unroll
                for (int ii = 0; ii < 8; ++ii) {
                    const int il = il8 * 8 + ii;
#pragma unroll
                    for (int mt = 0; mt < 4; ++mt) {
                        half8 a = x2f[mt] * x1f[mt][ii];   // 4 pk_mul per MFMA... shared W frag
                        acc[mt] = __builtin_amdgcn_mfma_f32_32x32x16_f16(a, wbuf[il & 3], acc[mt], 0, 0, 0);
                    }
                    wbuf[il & 3] = wb[woff + (unsigned)(il + 4) * 64];
                }
                __builtin_amdgcn_sched_barrier(0);   // bound hoist window (spill insurance)
            }
        }
    }

    // ---- split-K combine (via x2t region, dead now) -----------------------
    __syncthreads();                  // everyone done reading x2t / x1th
    float4t* xch = (float4t*)x2t;     // 2 kw=1 waves x 16 KB = 32 KB <= 33280 B
    if (kw == 1) {
#pragma unroll
        for (int mt = 0; mt < 4; ++mt)
#pragma unroll
            for (int r4 = 0; r4 < 4; ++r4) {
                float4t v = {acc[mt][r4*4+0], acc[mt][r4*4+1],
                             acc[mt][r4*4+2], acc[mt][r4*4+3]};
                xch[(wcol * 16 + mt * 4 + r4) * 64 + lane] = v;
            }
    }
    __syncthreads();
    if (kw == 0) {
#pragma unroll
        for (int mt = 0; mt < 4; ++mt)
#pragma unroll
            for (int r4 = 0; r4 < 4; ++r4) {
                float4t v = xch[(wcol * 16 + mt * 4 + r4) * 64 + lane];
                acc[mt][r4*4+0] += v[0]; acc[mt][r4*4+1] += v[1];
                acc[mt][r4*4+2] += v[2]; acc[mt][r4*4+3] += v[3];
            }

        // ---- epilogue: store y (f16) + per-o stats ------------------------
        // C/D 32x32 layout: col = lane&31, row = (r&3) + 8*(r>>2) + 4*q1.
        float sum = 0.f, sq = 0.f;
        int colg = ntile * 32 + nn;
#pragma unroll
        for (int mt = 0; mt < 4; ++mt) {
#pragma unroll
            for (int r = 0; r < 16; ++r) {
                int rl = (r & 3) + 8 * (r >> 2) + 4 * q1;
                size_t row = (size_t)p * Bsz + m0 + mt * 32 + rl;
                float v = acc[mt][r];
                sum += v; sq += v * v;
                yws[row * Fdim + colg] = (_Float16)v;
            }
        }
        sum += __shfl_xor(sum, 32, 64);
        sq  += __shfl_xor(sq, 32, 64);
        if (q1 == 0) {
            atomicAdd(&ssum[p * Fdim + colg], sum);
            atomicAdd(&ssq [p * Fdim + colg], sq);
        }
    }
}

// ---------------------------------------------------------------------------
// Kernel 3: BN (train-mode batch stats, biased var) + ReLU, f16 y -> fp32 out.
// ---------------------------------------------------------------------------
__global__ __launch_bounds__(256) void bnrelu(const _Float16* __restrict__ yws,
                                              const float* __restrict__ ssum,
                                              const float* __restrict__ ssq,
                                              const float* __restrict__ gamma,
                                              const float* __restrict__ beta,
                                              float* __restrict__ out) {
    __shared__ float gs[128], sh[128];
    size_t ebase = (size_t)blockIdx.x * 1024;
    int p = (int)(ebase >> 20);            // B*F = 2^20
    int t = threadIdx.x;
    if (t < 128) {
        float mean = ssum[p * Fdim + t] * (1.0f / 8192.0f);
        float var  = ssq [p * Fdim + t] * (1.0f / 8192.0f) - mean * mean;
        float g    = gamma[t] * rsqrtf(var + EPSI);
        gs[t] = g;
        sh[t] = beta[t] - g * mean;
    }
    __syncthreads();
    size_t e0 = ebase + (size_t)t * 4;
    int o0 = (int)(e0 & 127);
    half4t y = *(const half4t*)(yws + e0);
    float4t r;
#pragma unroll
    for (int l = 0; l < 4; ++l) {
        float v = fmaf(gs[o0 + l], (float)y[l], sh[o0 + l]);
        r[l] = v > 0.f ? v : 0.f;
    }
    *(float4t*)(out + e0) = r;
}

// ---------------------------------------------------------------------------
extern "C" void kernel_launch(void* const* d_in, const int* in_sizes, int n_in,
                              void* d_out, int out_size, void* d_ws, size_t ws_size,
                              hipStream_t stream) {
    const float* x     = (const float*)d_in[0];
    const float* W     = (const float*)d_in[1];
    // d_in[2] = linear bias b: mathematically cancelled by train-mode BN.
    const float* gamma = (const float*)d_in[3];
    const float* beta  = (const float*)d_in[4];
    float* out = (float*)d_out;

    // Layout: Wws FIRST so the W-stream's <=4 KB K-tail overshoot lands in
    // yws (allocated, values discarded) instead of past the workspace.
    char* ws = (char*)d_ws;
    _Float16* Wws = (_Float16*)ws;                       // 128*16384*2  =  4,194,304 B
    _Float16* yws = (_Float16*)(ws + 4194304);           // 6*8192*128*2 = 12,582,912 B
    float*    ssum = (float*)(ws + 16777216);            // 768 floats
    float*    ssq  = ssum + Pn * Fdim;                   // 768 floats

    (void)hipMemsetAsync(ssum, 0, 2 * Pn * Fdim * sizeof(float), stream);
    wprep<<<1024, 256, 0, stream>>>(W, Wws);
    gemm<<<768, 256, 0, stream>>>(x, Wws, yws, ssum, ssq);
    bnrelu<<<6144, 256, 0, stream>>>(yws, ssum, ssq, gamma, beta, out);
}